// Round 4
// baseline (714.232 us; speedup 1.0000x reference)
//
#include <hip/hip_runtime.h>
#include <hip/hip_bf16.h>

// Problem dims (fixed by reference)
#define B_  256
#define T_  250
#define D_  700
#define H_  1024
#define O_  20
#define KP  704          // K padded to multiple of 32 (22 K-steps of BK=32)
#define M_  64000        // B_*T_
#define NT  22           // K-tiles of BK=32

typedef __attribute__((ext_vector_type(8))) short bf16x8;
typedef __attribute__((ext_vector_type(4))) float f32x4;

// async global->LDS, 16B per lane (LDS dest = wave-uniform base + lane*16)
__device__ __forceinline__ void gl_lds16(const void* g, void* l) {
    __builtin_amdgcn_global_load_lds(
        (const __attribute__((address_space(1))) unsigned int*)g,
        (__attribute__((address_space(3))) unsigned int*)l, 16, 0, 0);
}

// ---------------------------------------------------------------------------
// Kernel A: split fp32 -> bf16 hi/lo, zero-padding K from Kin to Kout.
// ---------------------------------------------------------------------------
__global__ void split_convert(const float* __restrict__ src,
                              unsigned short* __restrict__ hi,
                              unsigned short* __restrict__ lo,
                              int M, int Kin, int Kout)
{
    int idx = blockIdx.x * blockDim.x + threadIdx.x;
    int chunks = Kout >> 3;
    int total = M * chunks;
    if (idx >= total) return;
    int m  = idx / chunks;
    int c  = idx - m * chunks;
    int d0 = c << 3;
    float x[8];
    if (d0 + 8 <= Kin) {
        const float4* p = (const float4*)(src + (long)m * Kin + d0);
        float4 v0 = p[0], v1 = p[1];
        x[0] = v0.x; x[1] = v0.y; x[2] = v0.z; x[3] = v0.w;
        x[4] = v1.x; x[5] = v1.y; x[6] = v1.z; x[7] = v1.w;
    } else {
#pragma unroll
        for (int e = 0; e < 8; ++e) {
            int d = d0 + e;
            x[e] = (d < Kin) ? src[(long)m * Kin + d] : 0.0f;
        }
    }
    unsigned short h8[8], l8[8];
#pragma unroll
    for (int e = 0; e < 8; ++e) {
        __hip_bfloat16 h = __float2bfloat16(x[e]);
        float hf = __bfloat162float(h);
        __hip_bfloat16 lv = __float2bfloat16(x[e] - hf);
        h8[e] = *(unsigned short*)&h;
        l8[e] = *(unsigned short*)&lv;
    }
    long ob = (long)m * Kout + d0;
    *(uint4*)(hi + ob) = *(uint4*)h8;
    *(uint4*)(lo + ob) = *(uint4*)l8;
}

// ---------------------------------------------------------------------------
// Kernel B: split-bf16 GEMM, 256x256 tile, 8 waves, 2-gate schedule with
// counted vmcnt (T4, round-3: 350->271us, MfmaUtil 34->45%) PLUS round-9
// change: intra-gate LDS->MFMA software pipelining with counted lgkmcnt.
//   Round-3 cycle model: per K-tile MFMA=3090cyc, ds_read=2300cyc,
//   measured 7400 => reads and MFMA serialized (lgkm0 before every MFMA
//   block + barrier lockstep). Fix: issue ALL of a gate's ds_reads up
//   front in pinned FIFO groups (sched_barrier(0) between groups), then
//   wait with COUNTED lgkm so later reads drain under earlier MFMAs:
//   gate1: reads [bh4,a01:4 | bl4,a23:4]; lgkm(8)->16 MFMA; lgkm(4)->
//          8 MFMA; lgkm(0)->24 MFMA.
//   gate2: reads [a45:4 | a67:4]; lgkm(4)->24 MFMA; lgkm(0)->24 MFMA.
//   vmcnt ledger unchanged: issue order B(4),A0(2),A1(2) per tile;
//   gate1 entry vmcnt(2) [A1(t) in flight], gate2 entry vmcnt(6)
//   [B,A0(t+1) in flight]; tail drains vmcnt(0) at gate2.
// T1 (bijective XCD swizzle), T2 (XOR both-sides LDS swizzle; conflict
// counter = 0), T5 (setprio) kept. 3-pass split math identical; pass
// order per i-pair is hh,lh,hl (operand-readiness) — benign fp32 reorder.
// ---------------------------------------------------------------------------
#define MF(a,b,c) (c) = __builtin_amdgcn_mfma_f32_16x16x32_bf16((a),(b),(c),0,0,0)
#define MF4(a, bb, accp) do { \
    MF(a, bb[0], accp[0]); MF(a, bb[1], accp[1]); \
    MF(a, bb[2], accp[2]); MF(a, bb[3], accp[3]); } while (0)

__global__ __launch_bounds__(512, 2) void gemm256(
    const unsigned short* __restrict__ Ahi, const unsigned short* __restrict__ Alo,
    const unsigned short* __restrict__ Bhi, const unsigned short* __restrict__ Blo,
    const float* __restrict__ bias, float* __restrict__ C)
{
    // 4 x 32 KB = 128 KB total, each [2 buf][256 rows][32 k] bf16
    __shared__ __align__(16) unsigned short sAh[2 * 8192];
    __shared__ __align__(16) unsigned short sAl[2 * 8192];
    __shared__ __align__(16) unsigned short sBh[2 * 8192];
    __shared__ __align__(16) unsigned short sBl[2 * 8192];

    // XCD-aware bijective swizzle: 1000 % 8 == 0 -> chunks of 125 per XCD
    const int bid = blockIdx.x;
    const int wg  = (bid & 7) * 125 + (bid >> 3);
    const int mblk = wg >> 2;        // 0..249
    const int nblk = wg & 3;         // 0..3

    const int t    = threadIdx.x;
    const int wave = t >> 6, lane = t & 63;
    const int wr = wave >> 2, wc = wave & 3;     // 2 (M) x 4 (N) waves

    // --- staging geometry: chunk = 16 rows x 32 k = 1 KB (one gl_lds16/wave)
    const int  rowoff = lane >> 2;                      // 0..15 within chunk
    const int  slotl  = (lane & 3) ^ ((lane >> 3) & 3); // inverse-swizzled slot
    const long GCH    = 16L * KP;                       // global row step/chunk
    const long gA     = (long)(mblk * 256 + rowoff) * KP + slotl * 8;
    const long gB     = (long)(nblk * 256 + rowoff) * KP + slotl * 8;
    const int  ldsO   = lane * 8;                       // + chunk*512 + buf
    // per-wave chunk assignment (issue groups)
    const int  cB0 = 2 * wave, cB1 = 2 * wave + 1;      // B chunks (gate-1)
    const int  cA0 = (wave < 4) ? wave : wave + 4;      // A rows 0-63,128-191
    const int  cA1 = cA0 + 4;                           // A rows 64-127,192-255

    const unsigned short* gBh = Bhi + gB;
    const unsigned short* gBl = Blo + gB;
    const unsigned short* gAh = Ahi + gA;
    const unsigned short* gAl = Alo + gA;

    auto issueB = [&](long ko, int bufo) {
        gl_lds16(gBh + (long)cB0 * GCH + ko, &sBh[bufo + cB0 * 512 + ldsO]);
        gl_lds16(gBh + (long)cB1 * GCH + ko, &sBh[bufo + cB1 * 512 + ldsO]);
        gl_lds16(gBl + (long)cB0 * GCH + ko, &sBl[bufo + cB0 * 512 + ldsO]);
        gl_lds16(gBl + (long)cB1 * GCH + ko, &sBl[bufo + cB1 * 512 + ldsO]);
    };
    auto issueA0 = [&](long ko, int bufo) {
        gl_lds16(gAh + (long)cA0 * GCH + ko, &sAh[bufo + cA0 * 512 + ldsO]);
        gl_lds16(gAl + (long)cA0 * GCH + ko, &sAl[bufo + cA0 * 512 + ldsO]);
    };
    auto issueA1 = [&](long ko, int bufo) {
        gl_lds16(gAh + (long)cA1 * GCH + ko, &sAh[bufo + cA1 * 512 + ldsO]);
        gl_lds16(gAl + (long)cA1 * GCH + ko, &sAl[bufo + cA1 * 512 + ldsO]);
    };

    // --- fragment read offsets (swizzled; involution with slotl) ---
    const int fr   = lane & 15, fq = lane >> 4;
    const int fxor = ((fq ^ ((fr >> 1) & 3)) << 3);
    const int abase = (wr * 128 + fr) * 32 + fxor;      // + i*512 + buf
    const int bbase = (wc * 64 + fr) * 32 + fxor;       // + j*512 + buf

    f32x4 acc[8][4];
#pragma unroll
    for (int i = 0; i < 8; ++i)
#pragma unroll
        for (int j = 0; j < 4; ++j) acc[i][j] = (f32x4){0.f, 0.f, 0.f, 0.f};

    // --- prologue: stage tile 0 into buffer 0 (issue order B, A0, A1) ---
    issueB(0, 0); issueA0(0, 0); issueA1(0, 0);

    for (int tt = 0; tt < NT; ++tt) {
        const int  cur = (tt & 1) ? 8192 : 0;
        const int  nxt = 8192 - cur;
        const long ksn = (long)(tt + 1) * 32;   // next tile k-offset (elements)
        const bool pf  = (tt + 1 < NT);

        // =============== GATE 1 (i-subtiles 0..3) ===============
        // own B(t)+A0(t) landed; A1(t) (2 newest vmem) stays in flight
        asm volatile("s_waitcnt vmcnt(2)" ::: "memory");
        __builtin_amdgcn_s_barrier();
        // read group 1 (FIFO oldest 8): bh[4], a0h,a0l,a1h,a1l
        bf16x8 bh[4], bl[4];
        bh[0] = *(const bf16x8*)&sBh[cur + bbase + 0 * 512];
        bh[1] = *(const bf16x8*)&sBh[cur + bbase + 1 * 512];
        bh[2] = *(const bf16x8*)&sBh[cur + bbase + 2 * 512];
        bh[3] = *(const bf16x8*)&sBh[cur + bbase + 3 * 512];
        bf16x8 a0h = *(const bf16x8*)&sAh[cur + abase + 0 * 512];
        bf16x8 a0l = *(const bf16x8*)&sAl[cur + abase + 0 * 512];
        bf16x8 a1h = *(const bf16x8*)&sAh[cur + abase + 1 * 512];
        bf16x8 a1l = *(const bf16x8*)&sAl[cur + abase + 1 * 512];
        __builtin_amdgcn_sched_barrier(0);
        // read group 2 (FIFO newest 8): bl[4], a2h,a2l,a3h,a3l
        bl[0] = *(const bf16x8*)&sBl[cur + bbase + 0 * 512];
        bl[1] = *(const bf16x8*)&sBl[cur + bbase + 1 * 512];
        bl[2] = *(const bf16x8*)&sBl[cur + bbase + 2 * 512];
        bl[3] = *(const bf16x8*)&sBl[cur + bbase + 3 * 512];
        bf16x8 a2h = *(const bf16x8*)&sAh[cur + abase + 2 * 512];
        bf16x8 a2l = *(const bf16x8*)&sAl[cur + abase + 2 * 512];
        bf16x8 a3h = *(const bf16x8*)&sAh[cur + abase + 3 * 512];
        bf16x8 a3l = *(const bf16x8*)&sAl[cur + abase + 3 * 512];
        __builtin_amdgcn_sched_barrier(0);
        if (pf) issueB(ksn, nxt);
        // group 1 ready; group 2 (8 ds ops) still in flight under MFMA
        asm volatile("s_waitcnt lgkmcnt(8)" ::: "memory");
        __builtin_amdgcn_sched_barrier(0);
        __builtin_amdgcn_s_setprio(1);
        MF4(a0h, bh, acc[0]); MF4(a1h, bh, acc[1]);   // hh  (16 MFMA)
        MF4(a0l, bh, acc[0]); MF4(a1l, bh, acc[1]);   // lh
        __builtin_amdgcn_s_setprio(0);
        // bl ready; a23 (4 ds ops) still in flight
        asm volatile("s_waitcnt lgkmcnt(4)" ::: "memory");
        __builtin_amdgcn_sched_barrier(0);
        __builtin_amdgcn_s_setprio(1);
        MF4(a0h, bl, acc[0]); MF4(a1h, bl, acc[1]);   // hl  (8 MFMA)
        __builtin_amdgcn_s_setprio(0);
        if (pf) issueA0(ksn, nxt);
        asm volatile("s_waitcnt lgkmcnt(0)" ::: "memory");
        __builtin_amdgcn_sched_barrier(0);
        __builtin_amdgcn_s_setprio(1);
        MF4(a2h, bh, acc[2]); MF4(a3h, bh, acc[3]);   // (24 MFMA)
        MF4(a2l, bh, acc[2]); MF4(a3l, bh, acc[3]);
        MF4(a2h, bl, acc[2]); MF4(a3h, bl, acc[3]);
        __builtin_amdgcn_s_setprio(0);

        // =============== GATE 2 (i-subtiles 4..7) ===============
        // drain A1(t); leave B(t+1)+A0(t+1) = 6 in flight (tail: drain all)
        if (pf) { asm volatile("s_waitcnt vmcnt(6)" ::: "memory"); }
        else    { asm volatile("s_waitcnt vmcnt(0)" ::: "memory"); }
        __builtin_amdgcn_s_barrier();
        // read group 1: a45
        bf16x8 a4h = *(const bf16x8*)&sAh[cur + abase + 4 * 512];
        bf16x8 a4l = *(const bf16x8*)&sAl[cur + abase + 4 * 512];
        bf16x8 a5h = *(const bf16x8*)&sAh[cur + abase + 5 * 512];
        bf16x8 a5l = *(const bf16x8*)&sAl[cur + abase + 5 * 512];
        __builtin_amdgcn_sched_barrier(0);
        // read group 2: a67
        bf16x8 a6h = *(const bf16x8*)&sAh[cur + abase + 6 * 512];
        bf16x8 a6l = *(const bf16x8*)&sAl[cur + abase + 6 * 512];
        bf16x8 a7h = *(const bf16x8*)&sAh[cur + abase + 7 * 512];
        bf16x8 a7l = *(const bf16x8*)&sAl[cur + abase + 7 * 512];
        __builtin_amdgcn_sched_barrier(0);
        if (pf) issueA1(ksn, nxt);
        // a45 ready; a67 (4 ds ops) in flight under MFMA
        asm volatile("s_waitcnt lgkmcnt(4)" ::: "memory");
        __builtin_amdgcn_sched_barrier(0);
        __builtin_amdgcn_s_setprio(1);
        MF4(a4h, bh, acc[4]); MF4(a5h, bh, acc[5]);   // (24 MFMA)
        MF4(a4l, bh, acc[4]); MF4(a5l, bh, acc[5]);
        MF4(a4h, bl, acc[4]); MF4(a5h, bl, acc[5]);
        __builtin_amdgcn_s_setprio(0);
        asm volatile("s_waitcnt lgkmcnt(0)" ::: "memory");
        __builtin_amdgcn_sched_barrier(0);
        __builtin_amdgcn_s_setprio(1);
        MF4(a6h, bh, acc[6]); MF4(a7h, bh, acc[7]);   // (24 MFMA)
        MF4(a6l, bh, acc[6]); MF4(a7l, bh, acc[7]);
        MF4(a6h, bl, acc[6]); MF4(a7h, bl, acc[7]);
        __builtin_amdgcn_s_setprio(0);
    }

    // --- epilogue ---
    const int r0 = mblk * 256 + wr * 128 + fq * 4;
    const int cc = nblk * 256 + wc * 64 + fr;
#pragma unroll
    for (int j = 0; j < 4; ++j) {
        int col = cc + j * 16;
        float bv = bias[col];
#pragma unroll
        for (int i = 0; i < 8; ++i) {
            int row = r0 + i * 16;
#pragma unroll
            for (int r = 0; r < 4; ++r)
                C[(long)(row + r) * H_ + col] = acc[i][j][r] + bv;
        }
    }
}

// ---------------------------------------------------------------------------
// Kernel C1: layer-1 LIF scan. Ring depth 6.
// ---------------------------------------------------------------------------
__global__ __launch_bounds__(256) void lif_spikes(
    const float* __restrict__ d1,    // [B*T, H]
    const float* __restrict__ tau1,
    unsigned long long* __restrict__ spk)  // [B*T, 16]
{
    const int b    = blockIdx.y;
    const int h    = blockIdx.x * 256 + threadIdx.x;
    const int lane = threadIdx.x & 63;
    const int widx = blockIdx.x * 4 + (threadIdx.x >> 6);

    float tv  = tau1[h];
    float a1  = 1.0f / (1.0f + __expf(-tv));
    float om1 = 1.0f - a1;
    float mem = 0.f, sp = 0.f;

    const float* dp = d1 + (long)b * T_ * H_ + h;
    unsigned long long* op = spk + (long)b * T_ * 16 + widx;

    float p0 = dp[0],        p1 = dp[1L * H_], p2 = dp[2L * H_];
    float p3 = dp[3L * H_],  p4 = dp[4L * H_], p5 = dp[5L * H_];

    for (int ts = 0; ts < T_; ++ts) {
        float cur = p0;
        p0 = p1; p1 = p2; p2 = p3; p3 = p4; p4 = p5;
        int nts = ts + 6; nts = (nts < T_) ? nts : (T_ - 1);
        p5 = dp[(long)nts * H_];

        mem = mem * a1 + om1 * cur - sp;
        sp  = (mem > 1.0f) ? 1.0f : 0.0f;
        unsigned long long msk = __ballot(mem > 1.0f);
        if (lane == 0) op[(long)ts * 16] = msk;
    }
}

// ---------------------------------------------------------------------------
// Kernel C2: d2 dots. 2000 blocks x 32 rows, 2-row ILP.
// ---------------------------------------------------------------------------
__global__ __launch_bounds__(256) void readout_dots(
    const unsigned long long* __restrict__ spk,  // [M_, 16]
    const float* __restrict__ W2,                // [O_, H_]
    float* __restrict__ d2t)                     // idx o*M_ + ts*256 + b
{
    const int t = threadIdx.x, wave = t >> 6, lane = t & 63;

    float w2r[5][16];
#pragma unroll
    for (int oo = 0; oo < 5; ++oo)
#pragma unroll
        for (int q = 0; q < 4; ++q)
            *(float4*)&w2r[oo][4 * q] =
                *(const float4*)&W2[(wave * 5 + oo) * H_ + lane * 16 + 4 * q];

    const int rbase = blockIdx.x * 32;           // M_ = 2000*32
    int b0 = rbase / T_;
    int ts0 = rbase - b0 * T_;

    for (int i = 0; i < 32; i += 2) {
        int r0 = rbase + i, r1 = r0 + 1;
        unsigned long long bw0 = spk[(long)r0 * 16 + (lane >> 2)];
        unsigned long long bw1 = spk[(long)r1 * 16 + (lane >> 2)];
        unsigned int bits0 = (unsigned int)(bw0 >> ((lane & 3) * 16)) & 0xFFFFu;
        unsigned int bits1 = (unsigned int)(bw1 >> ((lane & 3) * 16)) & 0xFFFFu;
        float pa0[5] = {0, 0, 0, 0, 0}, pa1[5] = {0, 0, 0, 0, 0};
#pragma unroll
        for (int j = 0; j < 16; ++j) {
            float f0 = (bits0 >> j) & 1u ? 1.0f : 0.0f;
            float f1 = (bits1 >> j) & 1u ? 1.0f : 0.0f;
#pragma unroll
            for (int oo = 0; oo < 5; ++oo) {
                pa0[oo] = fmaf(f0, w2r[oo][j], pa0[oo]);
                pa1[oo] = fmaf(f1, w2r[oo][j], pa1[oo]);
            }
        }
#pragma unroll
        for (int m = 1; m < 64; m <<= 1)
#pragma unroll
            for (int oo = 0; oo < 5; ++oo) {
                pa0[oo] += __shfl_xor(pa0[oo], m, 64);
                pa1[oo] += __shfl_xor(pa1[oo], m, 64);
            }
        if (lane == 0) {
            int bA = b0, tsA = ts0 + i;
            if (tsA >= T_) { tsA -= T_; bA += 1; }   // rbase%2==0, i even: safe
            int bB = bA, tsB = tsA + 1;
            if (tsB >= T_) { tsB = 0; bB += 1; }
#pragma unroll
            for (int oo = 0; oo < 5; ++oo) {
                d2t[(long)(wave * 5 + oo) * M_ + tsA * 256 + bA] = pa0[oo];
                d2t[(long)(wave * 5 + oo) * M_ + tsB * 256 + bB] = pa1[oo];
            }
        }
    }
}

// ---------------------------------------------------------------------------
// Kernel C3: mem2 linear recurrence. grid (20 o x 4 b-chunks), 64 threads.
// ---------------------------------------------------------------------------
__global__ __launch_bounds__(64) void mem2_scan(
    const float* __restrict__ d2t,   // (o, ts, b)
    const float* __restrict__ tau2, const float* __restrict__ b2,
    float* __restrict__ m2t)         // (o, ts, b)
{
    const int o = blockIdx.x;                    // 0..19
    const int b = blockIdx.y * 64 + threadIdx.x; // 0..255
    float tv  = tau2[o];
    float a2  = 1.0f / (1.0f + __expf(-tv));
    float om2 = 1.0f - a2;
    float bv  = b2[o];

    const float* dp = d2t + (long)o * M_ + b;
    float*       mp = m2t + (long)o * M_ + b;
    float mem = 0.f;

    float p0 = dp[0], p1 = dp[256], p2 = dp[512], p3 = dp[768];
    for (int ts = 0; ts < T_; ++ts) {
        float cur = p0; p0 = p1; p1 = p2; p2 = p3;
        int nts = ts + 4; nts = (nts < T_) ? nts : (T_ - 1);
        p3 = dp[(long)nts * 256];
        mem = mem * a2 + om2 * (cur + bv);
        mp[(long)ts * 256] = mem;
    }
}

// ---------------------------------------------------------------------------
// Kernel C4: per-(b,ts) softmax in-register + per-b sum over ts via LDS.
// ---------------------------------------------------------------------------
__global__ __launch_bounds__(256) void softmax_acc(
    const float* __restrict__ m2t,   // (o, ts, b)
    float* __restrict__ out)         // [B_, O_]
{
    __shared__ float sp[T_][O_];     // 19.5 KB
    const int b  = blockIdx.x;
    const int ts = threadIdx.x;

    if (ts < T_) {
        if (ts > 10) {
            float m[O_];
#pragma unroll
            for (int o = 0; o < O_; ++o)
                m[o] = m2t[(long)o * M_ + ts * 256 + b];
            float mx = m[0];
#pragma unroll
            for (int o = 1; o < O_; ++o) mx = fmaxf(mx, m[o]);
            float s = 0.f;
#pragma unroll
            for (int o = 0; o < O_; ++o) { m[o] = __expf(m[o] - mx); s += m[o]; }
            float inv = 1.0f / s;
#pragma unroll
            for (int o = 0; o < O_; ++o) sp[ts][o] = m[o] * inv;
        } else {
#pragma unroll
            for (int o = 0; o < O_; ++o) sp[ts][o] = 0.f;
        }
    }
    __syncthreads();
    if (ts < O_) {
        float s = 0.f;
        for (int k = 11; k < T_; ++k) s += sp[k][ts];
        out[b * O_ + ts] = s;
    }
}

// ---------------------------------------------------------------------------
extern "C" void kernel_launch(void* const* d_in, const int* in_sizes, int n_in,
                              void* d_out, int out_size, void* d_ws, size_t ws_size,
                              hipStream_t stream)
{
    const float* X    = (const float*)d_in[0];
    const float* W1   = (const float*)d_in[1];
    const float* b1   = (const float*)d_in[2];
    const float* tau1 = (const float*)d_in[3];
    const float* W2   = (const float*)d_in[4];
    const float* b2   = (const float*)d_in[5];
    const float* tau2 = (const float*)d_in[6];
    float* out = (float*)d_out;

    unsigned short* Xhi  = (unsigned short*)d_ws;
    unsigned short* Xlo  = Xhi + (long)M_ * KP;
    unsigned short* W1hi = Xlo + (long)M_ * KP;
    unsigned short* W1lo = W1hi + (long)H_ * KP;
    float* d1 = (float*)(W1lo + (long)H_ * KP);  // [M_, H] fp32

    unsigned long long* spk = (unsigned long long*)Xhi;      // aliases X splits
    float* d2t = (float*)Xlo;                                // (safe: sequential)
    float* m2t = d2t + (long)O_ * M_;

    // 1. split conversions
    {
        int chunks = M_ * (KP / 8);
        split_convert<<<(chunks + 255) / 256, 256, 0, stream>>>(X, Xhi, Xlo, M_, D_, KP);
    }
    {
        int chunks = H_ * (KP / 8);
        split_convert<<<(chunks + 255) / 256, 256, 0, stream>>>(W1, W1hi, W1lo, H_, D_, KP);
    }

    // 2. d1 = X @ W1^T + b1  (256^2 tile, 1000 blocks = 250 m x 4 n)
    gemm256<<<dim3(1000), dim3(512), 0, stream>>>(Xhi, Xlo, W1hi, W1lo, b1, d1);

    // 3. layer-1 spike scan
    {
        dim3 grid(H_ / 256, B_);                 // (4, 256)
        lif_spikes<<<grid, 256, 0, stream>>>(d1, tau1, spk);
    }

    // 4. readout dots
    readout_dots<<<M_ / 32, 256, 0, stream>>>(spk, W2, d2t);

    // 5. mem2 linear scan
    {
        dim3 grid(O_, 4);
        mem2_scan<<<grid, 64, 0, stream>>>(d2t, tau2, b2, m2t);
    }

    // 6. softmax + accumulate
    softmax_acc<<<B_, 256, 0, stream>>>(m2t, out);
}

// Round 5
// 702.458 us; speedup vs baseline: 1.0168x; 1.0168x over previous
//
#include <hip/hip_runtime.h>
#include <hip/hip_bf16.h>

// Problem dims (fixed by reference)
#define B_  256
#define T_  250
#define D_  700
#define H_  1024
#define O_  20
#define KP  704          // K padded to multiple of 32 (22 K-steps of BK=32)
#define M_  64000        // B_*T_
#define NT  22           // K-tiles of BK=32

typedef __attribute__((ext_vector_type(8))) short bf16x8;
typedef __attribute__((ext_vector_type(4))) float f32x4;

// async global->LDS, 16B per lane (LDS dest = wave-uniform base + lane*16)
__device__ __forceinline__ void gl_lds16(const void* g, void* l) {
    __builtin_amdgcn_global_load_lds(
        (const __attribute__((address_space(1))) unsigned int*)g,
        (__attribute__((address_space(3))) unsigned int*)l, 16, 0, 0);
}

// ---------------------------------------------------------------------------
// Kernel A: split fp32 -> bf16 hi/lo, zero-padding K from Kin to Kout.
// ---------------------------------------------------------------------------
__global__ void split_convert(const float* __restrict__ src,
                              unsigned short* __restrict__ hi,
                              unsigned short* __restrict__ lo,
                              int M, int Kin, int Kout)
{
    int idx = blockIdx.x * blockDim.x + threadIdx.x;
    int chunks = Kout >> 3;
    int total = M * chunks;
    if (idx >= total) return;
    int m  = idx / chunks;
    int c  = idx - m * chunks;
    int d0 = c << 3;
    float x[8];
    if (d0 + 8 <= Kin) {
        const float4* p = (const float4*)(src + (long)m * Kin + d0);
        float4 v0 = p[0], v1 = p[1];
        x[0] = v0.x; x[1] = v0.y; x[2] = v0.z; x[3] = v0.w;
        x[4] = v1.x; x[5] = v1.y; x[6] = v1.z; x[7] = v1.w;
    } else {
#pragma unroll
        for (int e = 0; e < 8; ++e) {
            int d = d0 + e;
            x[e] = (d < Kin) ? src[(long)m * Kin + d] : 0.0f;
        }
    }
    unsigned short h8[8], l8[8];
#pragma unroll
    for (int e = 0; e < 8; ++e) {
        __hip_bfloat16 h = __float2bfloat16(x[e]);
        float hf = __bfloat162float(h);
        __hip_bfloat16 lv = __float2bfloat16(x[e] - hf);
        h8[e] = *(unsigned short*)&h;
        l8[e] = *(unsigned short*)&lv;
    }
    long ob = (long)m * Kout + d0;
    *(uint4*)(hi + ob) = *(uint4*)h8;
    *(uint4*)(lo + ob) = *(uint4*)l8;
}

// ---------------------------------------------------------------------------
// Kernel B: split-bf16 GEMM, 256x256 tile, 8 waves, 2-gate schedule, counted
// vmcnt (T4; R3 350->271us) + round-10 change: FULL consumption-ordered
// fine lgkm ladder.
//   R4 post-mortem: coarse lgkm(8)/(4)/(0) ladder -> 254us, MfmaUtil 49%.
//   With 128KB LDS there is only 1 block/CU (2 waves/SIMD): no TLP to hide
//   the gate-head ds_read burst; LDS unit (~2900cyc/tile incl. gl_lds
//   writes) and MFMA pipe (~3725cyc/tile) were still ~serialized (7094
//   measured). Fix: issue all 16 gate-1 reads in exact consumption order
//   (bh0-3,a0h,a1h,a0l,a1l,bl0-3,a2h,a3h,a2l,a3l; DS completes in-order
//   per wave), then ladder: lgkm(11)->MF4(a0h,bh) ... one counted wait per
//   4-MFMA cluster, sched_barrier(0)-pinned, so 8-11 reads always drain
//   UNDER the MFMAs. Gate 2: 8 reads, 8-step ladder.
//   Per-acc MFMA order unchanged (hh->lh->hl) => bitwise-identical d1.
//   vmcnt ledger unchanged: issue B(4),A0(2),A1(2)/tile; gate1 vmcnt(2),
//   gate2 vmcnt(6); tail vmcnt(0).
// T1 (bijective XCD swizzle), T2 (XOR LDS swizzle; conflict ctr = 0),
// T5 (setprio around each gate's ladder) kept.
// ---------------------------------------------------------------------------
#define MF(a,b,c) (c) = __builtin_amdgcn_mfma_f32_16x16x32_bf16((a),(b),(c),0,0,0)
#define MF4(a, bb, accp) do { \
    MF(a, bb[0], accp[0]); MF(a, bb[1], accp[1]); \
    MF(a, bb[2], accp[2]); MF(a, bb[3], accp[3]); } while (0)
#define PIN() __builtin_amdgcn_sched_barrier(0)
#define LGKM(n) do { \
    asm volatile("s_waitcnt lgkmcnt(" #n ")" ::: "memory"); PIN(); } while (0)

__global__ __launch_bounds__(512, 2) void gemm256(
    const unsigned short* __restrict__ Ahi, const unsigned short* __restrict__ Alo,
    const unsigned short* __restrict__ Bhi, const unsigned short* __restrict__ Blo,
    const float* __restrict__ bias, float* __restrict__ C)
{
    // 4 x 32 KB = 128 KB total, each [2 buf][256 rows][32 k] bf16
    __shared__ __align__(16) unsigned short sAh[2 * 8192];
    __shared__ __align__(16) unsigned short sAl[2 * 8192];
    __shared__ __align__(16) unsigned short sBh[2 * 8192];
    __shared__ __align__(16) unsigned short sBl[2 * 8192];

    // XCD-aware bijective swizzle: 1000 % 8 == 0 -> chunks of 125 per XCD
    const int bid = blockIdx.x;
    const int wg  = (bid & 7) * 125 + (bid >> 3);
    const int mblk = wg >> 2;        // 0..249
    const int nblk = wg & 3;         // 0..3

    const int t    = threadIdx.x;
    const int wave = t >> 6, lane = t & 63;
    const int wr = wave >> 2, wc = wave & 3;     // 2 (M) x 4 (N) waves

    // --- staging geometry: chunk = 16 rows x 32 k = 1 KB (one gl_lds16/wave)
    const int  rowoff = lane >> 2;                      // 0..15 within chunk
    const int  slotl  = (lane & 3) ^ ((lane >> 3) & 3); // inverse-swizzled slot
    const long GCH    = 16L * KP;                       // global row step/chunk
    const long gA     = (long)(mblk * 256 + rowoff) * KP + slotl * 8;
    const long gB     = (long)(nblk * 256 + rowoff) * KP + slotl * 8;
    const int  ldsO   = lane * 8;                       // + chunk*512 + buf
    // per-wave chunk assignment (issue groups)
    const int  cB0 = 2 * wave, cB1 = 2 * wave + 1;      // B chunks (gate-1)
    const int  cA0 = (wave < 4) ? wave : wave + 4;      // A rows 0-63,128-191
    const int  cA1 = cA0 + 4;                           // A rows 64-127,192-255

    const unsigned short* gBh = Bhi + gB;
    const unsigned short* gBl = Blo + gB;
    const unsigned short* gAh = Ahi + gA;
    const unsigned short* gAl = Alo + gA;

    auto issueB = [&](long ko, int bufo) {
        gl_lds16(gBh + (long)cB0 * GCH + ko, &sBh[bufo + cB0 * 512 + ldsO]);
        gl_lds16(gBh + (long)cB1 * GCH + ko, &sBh[bufo + cB1 * 512 + ldsO]);
        gl_lds16(gBl + (long)cB0 * GCH + ko, &sBl[bufo + cB0 * 512 + ldsO]);
        gl_lds16(gBl + (long)cB1 * GCH + ko, &sBl[bufo + cB1 * 512 + ldsO]);
    };
    auto issueA0 = [&](long ko, int bufo) {
        gl_lds16(gAh + (long)cA0 * GCH + ko, &sAh[bufo + cA0 * 512 + ldsO]);
        gl_lds16(gAl + (long)cA0 * GCH + ko, &sAl[bufo + cA0 * 512 + ldsO]);
    };
    auto issueA1 = [&](long ko, int bufo) {
        gl_lds16(gAh + (long)cA1 * GCH + ko, &sAh[bufo + cA1 * 512 + ldsO]);
        gl_lds16(gAl + (long)cA1 * GCH + ko, &sAl[bufo + cA1 * 512 + ldsO]);
    };

    // --- fragment read offsets (swizzled; involution with slotl) ---
    const int fr   = lane & 15, fq = lane >> 4;
    const int fxor = ((fq ^ ((fr >> 1) & 3)) << 3);
    const int abase = (wr * 128 + fr) * 32 + fxor;      // + i*512 + buf
    const int bbase = (wc * 64 + fr) * 32 + fxor;       // + j*512 + buf

    f32x4 acc[8][4];
#pragma unroll
    for (int i = 0; i < 8; ++i)
#pragma unroll
        for (int j = 0; j < 4; ++j) acc[i][j] = (f32x4){0.f, 0.f, 0.f, 0.f};

    // --- prologue: stage tile 0 into buffer 0 (issue order B, A0, A1) ---
    issueB(0, 0); issueA0(0, 0); issueA1(0, 0);

    for (int tt = 0; tt < NT; ++tt) {
        const int  cur = (tt & 1) ? 8192 : 0;
        const int  nxt = 8192 - cur;
        const long ksn = (long)(tt + 1) * 32;   // next tile k-offset (elements)
        const bool pf  = (tt + 1 < NT);

        // =============== GATE 1 (i-subtiles 0..3) ===============
        // own B(t)+A0(t) landed; A1(t) (2 newest vmem) stays in flight
        asm volatile("s_waitcnt vmcnt(2)" ::: "memory");
        __builtin_amdgcn_s_barrier();
        // reads in consumption order (DS completes in-order per wave):
        // [bh0-3, a0h] [a1h] [a0l] [a1l] [bl0-3] [a2h] [a3h] [a2l] [a3l]
        bf16x8 bh[4], bl[4];
        bh[0] = *(const bf16x8*)&sBh[cur + bbase + 0 * 512];
        bh[1] = *(const bf16x8*)&sBh[cur + bbase + 1 * 512];
        bh[2] = *(const bf16x8*)&sBh[cur + bbase + 2 * 512];
        bh[3] = *(const bf16x8*)&sBh[cur + bbase + 3 * 512];
        bf16x8 a0h = *(const bf16x8*)&sAh[cur + abase + 0 * 512];
        PIN();
        bf16x8 a1h = *(const bf16x8*)&sAh[cur + abase + 1 * 512];
        PIN();
        bf16x8 a0l = *(const bf16x8*)&sAl[cur + abase + 0 * 512];
        PIN();
        bf16x8 a1l = *(const bf16x8*)&sAl[cur + abase + 1 * 512];
        PIN();
        bl[0] = *(const bf16x8*)&sBl[cur + bbase + 0 * 512];
        bl[1] = *(const bf16x8*)&sBl[cur + bbase + 1 * 512];
        bl[2] = *(const bf16x8*)&sBl[cur + bbase + 2 * 512];
        bl[3] = *(const bf16x8*)&sBl[cur + bbase + 3 * 512];
        PIN();
        bf16x8 a2h = *(const bf16x8*)&sAh[cur + abase + 2 * 512];
        PIN();
        bf16x8 a3h = *(const bf16x8*)&sAh[cur + abase + 3 * 512];
        PIN();
        bf16x8 a2l = *(const bf16x8*)&sAl[cur + abase + 2 * 512];
        PIN();
        bf16x8 a3l = *(const bf16x8*)&sAl[cur + abase + 3 * 512];
        PIN();
        if (pf) issueB(ksn, nxt);
        __builtin_amdgcn_s_setprio(1);
        // ladder: one counted wait per 4-MFMA cluster; 8-11 reads stay in
        // flight under the MFMAs. Per-acc pass order: hh, lh, hl (bitwise
        // identical to previous rounds).
        LGKM(11); MF4(a0h, bh, acc[0]); PIN();
        LGKM(10); MF4(a1h, bh, acc[1]); PIN();
        LGKM(9);  MF4(a0l, bh, acc[0]); PIN();
        LGKM(8);  MF4(a1l, bh, acc[1]); PIN();
        LGKM(4);  MF4(a0h, bl, acc[0]); MF4(a1h, bl, acc[1]); PIN();
        __builtin_amdgcn_s_setprio(0);
        if (pf) issueA0(ksn, nxt);
        __builtin_amdgcn_s_setprio(1);
        LGKM(3);  MF4(a2h, bh, acc[2]); PIN();
        LGKM(2);  MF4(a3h, bh, acc[3]); PIN();
        LGKM(1);  MF4(a2l, bh, acc[2]); PIN();
        LGKM(0);  MF4(a3l, bh, acc[3]);
                  MF4(a2h, bl, acc[2]); MF4(a3h, bl, acc[3]); PIN();
        __builtin_amdgcn_s_setprio(0);

        // =============== GATE 2 (i-subtiles 4..7) ===============
        // drain A1(t); leave B(t+1)+A0(t+1) = 6 in flight (tail: drain all)
        if (pf) { asm volatile("s_waitcnt vmcnt(6)" ::: "memory"); }
        else    { asm volatile("s_waitcnt vmcnt(0)" ::: "memory"); }
        __builtin_amdgcn_s_barrier();
        // reads in consumption order: a4h,a5h,a4l,a5l,a6h,a7h,a6l,a7l
        bf16x8 a4h = *(const bf16x8*)&sAh[cur + abase + 4 * 512];
        PIN();
        bf16x8 a5h = *(const bf16x8*)&sAh[cur + abase + 5 * 512];
        PIN();
        bf16x8 a4l = *(const bf16x8*)&sAl[cur + abase + 4 * 512];
        PIN();
        bf16x8 a5l = *(const bf16x8*)&sAl[cur + abase + 5 * 512];
        PIN();
        bf16x8 a6h = *(const bf16x8*)&sAh[cur + abase + 6 * 512];
        PIN();
        bf16x8 a7h = *(const bf16x8*)&sAh[cur + abase + 7 * 512];
        PIN();
        bf16x8 a6l = *(const bf16x8*)&sAl[cur + abase + 6 * 512];
        PIN();
        bf16x8 a7l = *(const bf16x8*)&sAl[cur + abase + 7 * 512];
        PIN();
        if (pf) issueA1(ksn, nxt);
        __builtin_amdgcn_s_setprio(1);
        LGKM(7); MF4(a4h, bh, acc[4]); PIN();
        LGKM(6); MF4(a5h, bh, acc[5]); PIN();
        LGKM(5); MF4(a4l, bh, acc[4]); PIN();
        LGKM(4); MF4(a5l, bh, acc[5]);
                 MF4(a4h, bl, acc[4]); MF4(a5h, bl, acc[5]); PIN();
        LGKM(3); MF4(a6h, bh, acc[6]); PIN();
        LGKM(2); MF4(a7h, bh, acc[7]); PIN();
        LGKM(1); MF4(a6l, bh, acc[6]); PIN();
        LGKM(0); MF4(a7l, bh, acc[7]);
                 MF4(a6h, bl, acc[6]); MF4(a7h, bl, acc[7]); PIN();
        __builtin_amdgcn_s_setprio(0);
    }

    // --- epilogue ---
    const int r0 = mblk * 256 + wr * 128 + fq * 4;
    const int cc = nblk * 256 + wc * 64 + fr;
#pragma unroll
    for (int j = 0; j < 4; ++j) {
        int col = cc + j * 16;
        float bv = bias[col];
#pragma unroll
        for (int i = 0; i < 8; ++i) {
            int row = r0 + i * 16;
#pragma unroll
            for (int r = 0; r < 4; ++r)
                C[(long)(row + r) * H_ + col] = acc[i][j][r] + bv;
        }
    }
}

// ---------------------------------------------------------------------------
// Kernel C1: layer-1 LIF scan. Ring depth 6.
// ---------------------------------------------------------------------------
__global__ __launch_bounds__(256) void lif_spikes(
    const float* __restrict__ d1,    // [B*T, H]
    const float* __restrict__ tau1,
    unsigned long long* __restrict__ spk)  // [B*T, 16]
{
    const int b    = blockIdx.y;
    const int h    = blockIdx.x * 256 + threadIdx.x;
    const int lane = threadIdx.x & 63;
    const int widx = blockIdx.x * 4 + (threadIdx.x >> 6);

    float tv  = tau1[h];
    float a1  = 1.0f / (1.0f + __expf(-tv));
    float om1 = 1.0f - a1;
    float mem = 0.f, sp = 0.f;

    const float* dp = d1 + (long)b * T_ * H_ + h;
    unsigned long long* op = spk + (long)b * T_ * 16 + widx;

    float p0 = dp[0],        p1 = dp[1L * H_], p2 = dp[2L * H_];
    float p3 = dp[3L * H_],  p4 = dp[4L * H_], p5 = dp[5L * H_];

    for (int ts = 0; ts < T_; ++ts) {
        float cur = p0;
        p0 = p1; p1 = p2; p2 = p3; p3 = p4; p4 = p5;
        int nts = ts + 6; nts = (nts < T_) ? nts : (T_ - 1);
        p5 = dp[(long)nts * H_];

        mem = mem * a1 + om1 * cur - sp;
        sp  = (mem > 1.0f) ? 1.0f : 0.0f;
        unsigned long long msk = __ballot(mem > 1.0f);
        if (lane == 0) op[(long)ts * 16] = msk;
    }
}

// ---------------------------------------------------------------------------
// Kernel C2: d2 dots. 2000 blocks x 32 rows, 2-row ILP.
// ---------------------------------------------------------------------------
__global__ __launch_bounds__(256) void readout_dots(
    const unsigned long long* __restrict__ spk,  // [M_, 16]
    const float* __restrict__ W2,                // [O_, H_]
    float* __restrict__ d2t)                     // idx o*M_ + ts*256 + b
{
    const int t = threadIdx.x, wave = t >> 6, lane = t & 63;

    float w2r[5][16];
#pragma unroll
    for (int oo = 0; oo < 5; ++oo)
#pragma unroll
        for (int q = 0; q < 4; ++q)
            *(float4*)&w2r[oo][4 * q] =
                *(const float4*)&W2[(wave * 5 + oo) * H_ + lane * 16 + 4 * q];

    const int rbase = blockIdx.x * 32;           // M_ = 2000*32
    int b0 = rbase / T_;
    int ts0 = rbase - b0 * T_;

    for (int i = 0; i < 32; i += 2) {
        int r0 = rbase + i, r1 = r0 + 1;
        unsigned long long bw0 = spk[(long)r0 * 16 + (lane >> 2)];
        unsigned long long bw1 = spk[(long)r1 * 16 + (lane >> 2)];
        unsigned int bits0 = (unsigned int)(bw0 >> ((lane & 3) * 16)) & 0xFFFFu;
        unsigned int bits1 = (unsigned int)(bw1 >> ((lane & 3) * 16)) & 0xFFFFu;
        float pa0[5] = {0, 0, 0, 0, 0}, pa1[5] = {0, 0, 0, 0, 0};
#pragma unroll
        for (int j = 0; j < 16; ++j) {
            float f0 = (bits0 >> j) & 1u ? 1.0f : 0.0f;
            float f1 = (bits1 >> j) & 1u ? 1.0f : 0.0f;
#pragma unroll
            for (int oo = 0; oo < 5; ++oo) {
                pa0[oo] = fmaf(f0, w2r[oo][j], pa0[oo]);
                pa1[oo] = fmaf(f1, w2r[oo][j], pa1[oo]);
            }
        }
#pragma unroll
        for (int m = 1; m < 64; m <<= 1)
#pragma unroll
            for (int oo = 0; oo < 5; ++oo) {
                pa0[oo] += __shfl_xor(pa0[oo], m, 64);
                pa1[oo] += __shfl_xor(pa1[oo], m, 64);
            }
        if (lane == 0) {
            int bA = b0, tsA = ts0 + i;
            if (tsA >= T_) { tsA -= T_; bA += 1; }   // rbase%2==0, i even: safe
            int bB = bA, tsB = tsA + 1;
            if (tsB >= T_) { tsB = 0; bB += 1; }
#pragma unroll
            for (int oo = 0; oo < 5; ++oo) {
                d2t[(long)(wave * 5 + oo) * M_ + tsA * 256 + bA] = pa0[oo];
                d2t[(long)(wave * 5 + oo) * M_ + tsB * 256 + bB] = pa1[oo];
            }
        }
    }
}

// ---------------------------------------------------------------------------
// Kernel C3: mem2 linear recurrence. grid (20 o x 4 b-chunks), 64 threads.
// ---------------------------------------------------------------------------
__global__ __launch_bounds__(64) void mem2_scan(
    const float* __restrict__ d2t,   // (o, ts, b)
    const float* __restrict__ tau2, const float* __restrict__ b2,
    float* __restrict__ m2t)         // (o, ts, b)
{
    const int o = blockIdx.x;                    // 0..19
    const int b = blockIdx.y * 64 + threadIdx.x; // 0..255
    float tv  = tau2[o];
    float a2  = 1.0f / (1.0f + __expf(-tv));
    float om2 = 1.0f - a2;
    float bv  = b2[o];

    const float* dp = d2t + (long)o * M_ + b;
    float*       mp = m2t + (long)o * M_ + b;
    float mem = 0.f;

    float p0 = dp[0], p1 = dp[256], p2 = dp[512], p3 = dp[768];
    for (int ts = 0; ts < T_; ++ts) {
        float cur = p0; p0 = p1; p1 = p2; p2 = p3;
        int nts = ts + 4; nts = (nts < T_) ? nts : (T_ - 1);
        p3 = dp[(long)nts * 256];
        mem = mem * a2 + om2 * (cur + bv);
        mp[(long)ts * 256] = mem;
    }
}

// ---------------------------------------------------------------------------
// Kernel C4: per-(b,ts) softmax in-register + per-b sum over ts via LDS.
// ---------------------------------------------------------------------------
__global__ __launch_bounds__(256) void softmax_acc(
    const float* __restrict__ m2t,   // (o, ts, b)
    float* __restrict__ out)         // [B_, O_]
{
    __shared__ float sp[T_][O_];     // 19.5 KB
    const int b  = blockIdx.x;
    const int ts = threadIdx.x;

    if (ts < T_) {
        if (ts > 10) {
            float m[O_];
#pragma unroll
            for (int o = 0; o < O_; ++o)
                m[o] = m2t[(long)o * M_ + ts * 256 + b];
            float mx = m[0];
#pragma unroll
            for (int o = 1; o < O_; ++o) mx = fmaxf(mx, m[o]);
            float s = 0.f;
#pragma unroll
            for (int o = 0; o < O_; ++o) { m[o] = __expf(m[o] - mx); s += m[o]; }
            float inv = 1.0f / s;
#pragma unroll
            for (int o = 0; o < O_; ++o) sp[ts][o] = m[o] * inv;
        } else {
#pragma unroll
            for (int o = 0; o < O_; ++o) sp[ts][o] = 0.f;
        }
    }
    __syncthreads();
    if (ts < O_) {
        float s = 0.f;
        for (int k = 11; k < T_; ++k) s += sp[k][ts];
        out[b * O_ + ts] = s;
    }
}

// ---------------------------------------------------------------------------
extern "C" void kernel_launch(void* const* d_in, const int* in_sizes, int n_in,
                              void* d_out, int out_size, void* d_ws, size_t ws_size,
                              hipStream_t stream)
{
    const float* X    = (const float*)d_in[0];
    const float* W1   = (const float*)d_in[1];
    const float* b1   = (const float*)d_in[2];
    const float* tau1 = (const float*)d_in[3];
    const float* W2   = (const float*)d_in[4];
    const float* b2   = (const float*)d_in[5];
    const float* tau2 = (const float*)d_in[6];
    float* out = (float*)d_out;

    unsigned short* Xhi  = (unsigned short*)d_ws;
    unsigned short* Xlo  = Xhi + (long)M_ * KP;
    unsigned short* W1hi = Xlo + (long)M_ * KP;
    unsigned short* W1lo = W1hi + (long)H_ * KP;
    float* d1 = (float*)(W1lo + (long)H_ * KP);  // [M_, H] fp32

    unsigned long long* spk = (unsigned long long*)Xhi;      // aliases X splits
    float* d2t = (float*)Xlo;                                // (safe: sequential)
    float* m2t = d2t + (long)O_ * M_;

    // 1. split conversions
    {
        int chunks = M_ * (KP / 8);
        split_convert<<<(chunks + 255) / 256, 256, 0, stream>>>(X, Xhi, Xlo, M_, D_, KP);
    }
    {
        int chunks = H_ * (KP / 8);
        split_convert<<<(chunks + 255) / 256, 256, 0, stream>>>(W1, W1hi, W1lo, H_, D_, KP);
    }

    // 2. d1 = X @ W1^T + b1  (256^2 tile, 1000 blocks = 250 m x 4 n)
    gemm256<<<dim3(1000), dim3(512), 0, stream>>>(Xhi, Xlo, W1hi, W1lo, b1, d1);

    // 3. layer-1 spike scan
    {
        dim3 grid(H_ / 256, B_);                 // (4, 256)
        lif_spikes<<<grid, 256, 0, stream>>>(d1, tau1, spk);
    }

    // 4. readout dots
    readout_dots<<<M_ / 32, 256, 0, stream>>>(spk, W2, d2t);

    // 5. mem2 linear scan
    {
        dim3 grid(O_, 4);
        mem2_scan<<<grid, 64, 0, stream>>>(d2t, tau2, b2, m2t);
    }

    // 6. softmax + accumulate
    softmax_acc<<<B_, 256, 0, stream>>>(m2t, out);
}

// Round 6
// 670.511 us; speedup vs baseline: 1.0652x; 1.0476x over previous
//
#include <hip/hip_runtime.h>
#include <hip/hip_bf16.h>

// Problem dims (fixed by reference)
#define B_  256
#define T_  250
#define D_  700
#define H_  1024
#define O_  20
#define KP  704          // K padded to multiple of 32 (22 K-steps of BK=32)
#define M_  64000        // B_*T_
#define NT  22           // K-tiles of BK=32

typedef __attribute__((ext_vector_type(8))) short bf16x8;
typedef __attribute__((ext_vector_type(4))) float f32x4;

// async global->LDS, 16B per lane (LDS dest = wave-uniform base + lane*16)
__device__ __forceinline__ void gl_lds16(const void* g, void* l) {
    __builtin_amdgcn_global_load_lds(
        (const __attribute__((address_space(1))) unsigned int*)g,
        (__attribute__((address_space(3))) unsigned int*)l, 16, 0, 0);
}

// ---------------------------------------------------------------------------
// Kernel A: split fp32 -> bf16 hi/lo, zero-padding K from Kin to Kout.
// Round-11: only used for W1 now (3 MB); the X split (539 MB of HBM traffic)
// is fused into the GEMM's A-staging.
// ---------------------------------------------------------------------------
__global__ void split_convert(const float* __restrict__ src,
                              unsigned short* __restrict__ hi,
                              unsigned short* __restrict__ lo,
                              int M, int Kin, int Kout)
{
    int idx = blockIdx.x * blockDim.x + threadIdx.x;
    int chunks = Kout >> 3;
    int total = M * chunks;
    if (idx >= total) return;
    int m  = idx / chunks;
    int c  = idx - m * chunks;
    int d0 = c << 3;
    float x[8];
    if (d0 + 8 <= Kin) {
        const float4* p = (const float4*)(src + (long)m * Kin + d0);
        float4 v0 = p[0], v1 = p[1];
        x[0] = v0.x; x[1] = v0.y; x[2] = v0.z; x[3] = v0.w;
        x[4] = v1.x; x[5] = v1.y; x[6] = v1.z; x[7] = v1.w;
    } else {
#pragma unroll
        for (int e = 0; e < 8; ++e) {
            int d = d0 + e;
            x[e] = (d < Kin) ? src[(long)m * Kin + d] : 0.0f;
        }
    }
    unsigned short h8[8], l8[8];
#pragma unroll
    for (int e = 0; e < 8; ++e) {
        __hip_bfloat16 h = __float2bfloat16(x[e]);
        float hf = __bfloat162float(h);
        __hip_bfloat16 lv = __float2bfloat16(x[e] - hf);
        h8[e] = *(unsigned short*)&h;
        l8[e] = *(unsigned short*)&lv;
    }
    long ob = (long)m * Kout + d0;
    *(uint4*)(hi + ob) = *(uint4*)h8;
    *(uint4*)(lo + ob) = *(uint4*)l8;
}

// ---------------------------------------------------------------------------
// Kernel B: split-bf16 GEMM, 256x256 tile, 8 waves, 2-gate schedule with
// counted vmcnt (T4) + fine lgkm ladder (R5) + round-11 change:
// FUSED A-STAGING — A is read directly from X (fp32) and split to hi/lo
// in registers (T14 reg-staging), eliminating the separate X split kernel
// (539 MB HBM round-trip). Key invariants:
//   - vmem ledger UNCHANGED: per tile issue B(4 gl_lds), A0(2 dwordx4),
//     A1(2 dwordx4); gate waits vmcnt(6) [drain A1(t)] and vmcnt(2)
//     [drain B(t+1)+A0(t+1)] at the same program points as R5.
//   - split uses the SAME __float2bfloat16 sequence as split_convert in
//     the same element order -> bitwise-identical d1 (absmax stays 0).
//   - ds_write_b128 produces the identical linear LDS image gl_lds made
//     (slotl source pre-swizzle kept; fragment-read fxor unchanged).
//   - splits+writes sit between the existing counted vmcnt and the
//     barrier, drained by lgkmcnt(0), so ladder counts are untouched.
//   - k-tail 700..703: second 16B granule zero-filled (== split_convert's
//     zero-pad; B-side W1hi/lo are zero there anyway). No OOB reads.
// T1 (bijective XCD swizzle), T2 (XOR LDS swizzle; conflict ctr = 0),
// T5 (setprio) kept.
// ---------------------------------------------------------------------------
#define MF(a,b,c) (c) = __builtin_amdgcn_mfma_f32_16x16x32_bf16((a),(b),(c),0,0,0)
#define MF4(a, bb, accp) do { \
    MF(a, bb[0], accp[0]); MF(a, bb[1], accp[1]); \
    MF(a, bb[2], accp[2]); MF(a, bb[3], accp[3]); } while (0)
#define PIN() __builtin_amdgcn_sched_barrier(0)
#define LGKM(n) do { \
    asm volatile("s_waitcnt lgkmcnt(" #n ")" ::: "memory"); PIN(); } while (0)

__global__ __launch_bounds__(512, 2) void gemm256(
    const float* __restrict__ X,
    const unsigned short* __restrict__ Bhi, const unsigned short* __restrict__ Blo,
    const float* __restrict__ bias, float* __restrict__ C)
{
    // 4 x 32 KB = 128 KB total, each [2 buf][256 rows][32 k] bf16
    __shared__ __align__(16) unsigned short sAh[2 * 8192];
    __shared__ __align__(16) unsigned short sAl[2 * 8192];
    __shared__ __align__(16) unsigned short sBh[2 * 8192];
    __shared__ __align__(16) unsigned short sBl[2 * 8192];

    // XCD-aware bijective swizzle: 1000 % 8 == 0 -> chunks of 125 per XCD
    const int bid = blockIdx.x;
    const int wg  = (bid & 7) * 125 + (bid >> 3);
    const int mblk = wg >> 2;        // 0..249
    const int nblk = wg & 3;         // 0..3

    const int t    = threadIdx.x;
    const int wave = t >> 6, lane = t & 63;
    const int wr = wave >> 2, wc = wave & 3;     // 2 (M) x 4 (N) waves

    // --- staging geometry: chunk = 16 rows x 32 k (one 1KB LDS image/wave)
    const int  rowoff = lane >> 2;                      // 0..15 within chunk
    const int  slotl  = (lane & 3) ^ ((lane >> 3) & 3); // inverse-swizzled slot
    const int  slotk  = slotl * 8;                      // element offset in row
    const long GCH    = 16L * KP;                       // B row step/chunk (ushort)
    const long gB     = (long)(nblk * 256 + rowoff) * KP + slotk;
    const long gX     = (long)(mblk * 256 + rowoff) * D_ + slotk;  // fp32 elems
    const int  ldsO   = lane * 8;                       // + chunk*512 + buf
    // per-wave chunk assignment (issue groups)
    const int  cB0 = 2 * wave, cB1 = 2 * wave + 1;      // B chunks (gate-1)
    const int  cA0 = (wave < 4) ? wave : wave + 4;      // A rows 0-63,128-191
    const int  cA1 = cA0 + 4;                           // A rows 64-127,192-255

    const unsigned short* gBh = Bhi + gB;
    const unsigned short* gBl = Blo + gB;

    auto issueB = [&](long ko, int bufo) {
        gl_lds16(gBh + (long)cB0 * GCH + ko, &sBh[bufo + cB0 * 512 + ldsO]);
        gl_lds16(gBh + (long)cB1 * GCH + ko, &sBh[bufo + cB1 * 512 + ldsO]);
        gl_lds16(gBl + (long)cB0 * GCH + ko, &sBl[bufo + cB0 * 512 + ldsO]);
        gl_lds16(gBl + (long)cB1 * GCH + ko, &sBl[bufo + cB1 * 512 + ldsO]);
    };
    // A fp32 chunk load: exactly 2 vmem insts (ledger: same as 2 gl_lds).
    // Second granule zero-filled when its 4 k-values fall in the 700..703 pad.
    auto loadA = [&](long koE, int c, float4& r0, float4& r1) {
        const float* p = X + gX + (long)c * (16L * D_) + koE;
        r0 = *(const float4*)p;                       // k0 <= 696: always valid
        int k1 = (int)koE + slotk + 4;
        r1 = (float4){0.f, 0.f, 0.f, 0.f};
        if (k1 + 4 <= D_) r1 = *(const float4*)(p + 4);
    };
    // split fp32 -> (hi, lo) bf16 and write the 1KB LDS chunk image.
    // Identical arithmetic to split_convert -> bitwise-identical staging.
    auto splitWrite = [&](float4 r0, float4 r1, int bufo, int c) {
        float xs[8] = {r0.x, r0.y, r0.z, r0.w, r1.x, r1.y, r1.z, r1.w};
        unsigned short h8[8], l8[8];
#pragma unroll
        for (int e = 0; e < 8; ++e) {
            __hip_bfloat16 h = __float2bfloat16(xs[e]);
            float hf = __bfloat162float(h);
            __hip_bfloat16 lv = __float2bfloat16(xs[e] - hf);
            h8[e] = *(unsigned short*)&h;
            l8[e] = *(unsigned short*)&lv;
        }
        *(uint4*)&sAh[bufo + c * 512 + ldsO] = *(uint4*)h8;
        *(uint4*)&sAl[bufo + c * 512 + ldsO] = *(uint4*)l8;
    };

    // --- fragment read offsets (swizzled; involution with slotl) ---
    const int fr   = lane & 15, fq = lane >> 4;
    const int fxor = ((fq ^ ((fr >> 1) & 3)) << 3);
    const int abase = (wr * 128 + fr) * 32 + fxor;      // + i*512 + buf
    const int bbase = (wc * 64 + fr) * 32 + fxor;       // + j*512 + buf

    f32x4 acc[8][4];
#pragma unroll
    for (int i = 0; i < 8; ++i)
#pragma unroll
        for (int j = 0; j < 4; ++j) acc[i][j] = (f32x4){0.f, 0.f, 0.f, 0.f};

    float4 a0r0, a0r1, a1r0, a1r1;   // reg-staged A (a1r* is loop-carried)

    // --- prologue: tile 0 -> buffer 0 (vmem order: B, A0, A1) ---
    issueB(0, 0);
    loadA(0, cA0, a0r0, a0r1);
    loadA(0, cA1, a1r0, a1r1);
    PIN();
    asm volatile("s_waitcnt vmcnt(2)" ::: "memory");   // drain B(0)+A0(0)
    PIN();
    splitWrite(a0r0, a0r1, 0, cA0);
    asm volatile("s_waitcnt lgkmcnt(0)" ::: "memory");
    PIN();
    __builtin_amdgcn_s_barrier();
    // A1(0) globals still in flight (2 outstanding)

    for (int tt = 0; tt < NT; ++tt) {
        const int  cur = (tt & 1) ? 8192 : 0;
        const int  nxt = 8192 - cur;
        const long ksn = (long)(tt + 1) * 32;   // next tile k-offset (elements)
        const bool pf  = (tt + 1 < NT);

        // =============== GATE 1 (i-subtiles 0..3) ===============
        // (barrier at end of previous iteration / prologue; staged data
        //  for gate-1 is in LDS; A1(t) fp32 globals in flight)
        bf16x8 bh[4], bl[4];
        bh[0] = *(const bf16x8*)&sBh[cur + bbase + 0 * 512];
        bh[1] = *(const bf16x8*)&sBh[cur + bbase + 1 * 512];
        bh[2] = *(const bf16x8*)&sBh[cur + bbase + 2 * 512];
        bh[3] = *(const bf16x8*)&sBh[cur + bbase + 3 * 512];
        bf16x8 a0h = *(const bf16x8*)&sAh[cur + abase + 0 * 512];
        PIN();
        bf16x8 a1h = *(const bf16x8*)&sAh[cur + abase + 1 * 512];
        PIN();
        bf16x8 a0l = *(const bf16x8*)&sAl[cur + abase + 0 * 512];
        PIN();
        bf16x8 a1l = *(const bf16x8*)&sAl[cur + abase + 1 * 512];
        PIN();
        bl[0] = *(const bf16x8*)&sBl[cur + bbase + 0 * 512];
        bl[1] = *(const bf16x8*)&sBl[cur + bbase + 1 * 512];
        bl[2] = *(const bf16x8*)&sBl[cur + bbase + 2 * 512];
        bl[3] = *(const bf16x8*)&sBl[cur + bbase + 3 * 512];
        PIN();
        bf16x8 a2h = *(const bf16x8*)&sAh[cur + abase + 2 * 512];
        PIN();
        bf16x8 a3h = *(const bf16x8*)&sAh[cur + abase + 3 * 512];
        PIN();
        bf16x8 a2l = *(const bf16x8*)&sAl[cur + abase + 2 * 512];
        PIN();
        bf16x8 a3l = *(const bf16x8*)&sAl[cur + abase + 3 * 512];
        PIN();
        if (pf) issueB(ksn, nxt);
        __builtin_amdgcn_s_setprio(1);
        // ladder: one counted wait per cluster; per-acc pass order hh,lh,hl
        // (bitwise identical to previous rounds).
        LGKM(11); MF4(a0h, bh, acc[0]); PIN();
        LGKM(10); MF4(a1h, bh, acc[1]); PIN();
        LGKM(9);  MF4(a0l, bh, acc[0]); PIN();
        LGKM(8);  MF4(a1l, bh, acc[1]); PIN();
        LGKM(4);  MF4(a0h, bl, acc[0]); MF4(a1h, bl, acc[1]); PIN();
        __builtin_amdgcn_s_setprio(0);
        if (pf) loadA(ksn, cA0, a0r0, a0r1);   // A0(t+1) fp32 (2 vmem)
        PIN();
        __builtin_amdgcn_s_setprio(1);
        LGKM(3);  MF4(a2h, bh, acc[2]); PIN();
        LGKM(2);  MF4(a3h, bh, acc[3]); PIN();
        LGKM(1);  MF4(a2l, bh, acc[2]); PIN();
        LGKM(0);  MF4(a3l, bh, acc[3]);
                  MF4(a2h, bl, acc[2]); MF4(a3h, bl, acc[3]); PIN();
        __builtin_amdgcn_s_setprio(0);

        // gate-1 end: drain A1(t) fp32 globals (oldest 2), split into cur.
        if (pf) { asm volatile("s_waitcnt vmcnt(6)" ::: "memory"); }
        else    { asm volatile("s_waitcnt vmcnt(0)" ::: "memory"); }
        PIN();
        splitWrite(a1r0, a1r1, cur, cA1);
        asm volatile("s_waitcnt lgkmcnt(0)" ::: "memory");
        PIN();
        __builtin_amdgcn_s_barrier();

        // =============== GATE 2 (i-subtiles 4..7) ===============
        bf16x8 a4h = *(const bf16x8*)&sAh[cur + abase + 4 * 512];
        PIN();
        bf16x8 a5h = *(const bf16x8*)&sAh[cur + abase + 5 * 512];
        PIN();
        bf16x8 a4l = *(const bf16x8*)&sAl[cur + abase + 4 * 512];
        PIN();
        bf16x8 a5l = *(const bf16x8*)&sAl[cur + abase + 5 * 512];
        PIN();
        bf16x8 a6h = *(const bf16x8*)&sAh[cur + abase + 6 * 512];
        PIN();
        bf16x8 a7h = *(const bf16x8*)&sAh[cur + abase + 7 * 512];
        PIN();
        bf16x8 a6l = *(const bf16x8*)&sAl[cur + abase + 6 * 512];
        PIN();
        bf16x8 a7l = *(const bf16x8*)&sAl[cur + abase + 7 * 512];
        PIN();
        if (pf) loadA(ksn, cA1, a1r0, a1r1);   // A1(t+1) fp32 (2 vmem)
        PIN();
        __builtin_amdgcn_s_setprio(1);
        LGKM(7); MF4(a4h, bh, acc[4]); PIN();
        LGKM(6); MF4(a5h, bh, acc[5]); PIN();
        LGKM(5); MF4(a4l, bh, acc[4]); PIN();
        LGKM(4); MF4(a5l, bh, acc[5]);
                 MF4(a4h, bl, acc[4]); MF4(a5h, bl, acc[5]); PIN();
        LGKM(3); MF4(a6h, bh, acc[6]); PIN();
        LGKM(2); MF4(a7h, bh, acc[7]); PIN();
        LGKM(1); MF4(a6l, bh, acc[6]); PIN();
        LGKM(0); MF4(a7l, bh, acc[7]);
                 MF4(a6h, bl, acc[6]); MF4(a7h, bl, acc[7]); PIN();
        __builtin_amdgcn_s_setprio(0);

        // gate-2 end: drain B(t+1)+A0(t+1) (leave A1(t+1) in flight),
        // split A0(t+1) into nxt, publish, fence.
        if (pf) {
            asm volatile("s_waitcnt vmcnt(2)" ::: "memory");
            PIN();
            splitWrite(a0r0, a0r1, nxt, cA0);
            asm volatile("s_waitcnt lgkmcnt(0)" ::: "memory");
            PIN();
            __builtin_amdgcn_s_barrier();
        }
    }

    // --- epilogue ---
    const int r0 = mblk * 256 + wr * 128 + fq * 4;
    const int cc = nblk * 256 + wc * 64 + fr;
#pragma unroll
    for (int j = 0; j < 4; ++j) {
        int col = cc + j * 16;
        float bv = bias[col];
#pragma unroll
        for (int i = 0; i < 8; ++i) {
            int row = r0 + i * 16;
#pragma unroll
            for (int r = 0; r < 4; ++r)
                C[(long)(row + r) * H_ + col] = acc[i][j][r] + bv;
        }
    }
}

// ---------------------------------------------------------------------------
// Kernel C1: layer-1 LIF scan. Ring depth 6.
// ---------------------------------------------------------------------------
__global__ __launch_bounds__(256) void lif_spikes(
    const float* __restrict__ d1,    // [B*T, H]
    const float* __restrict__ tau1,
    unsigned long long* __restrict__ spk)  // [B*T, 16]
{
    const int b    = blockIdx.y;
    const int h    = blockIdx.x * 256 + threadIdx.x;
    const int lane = threadIdx.x & 63;
    const int widx = blockIdx.x * 4 + (threadIdx.x >> 6);

    float tv  = tau1[h];
    float a1  = 1.0f / (1.0f + __expf(-tv));
    float om1 = 1.0f - a1;
    float mem = 0.f, sp = 0.f;

    const float* dp = d1 + (long)b * T_ * H_ + h;
    unsigned long long* op = spk + (long)b * T_ * 16 + widx;

    float p0 = dp[0],        p1 = dp[1L * H_], p2 = dp[2L * H_];
    float p3 = dp[3L * H_],  p4 = dp[4L * H_], p5 = dp[5L * H_];

    for (int ts = 0; ts < T_; ++ts) {
        float cur = p0;
        p0 = p1; p1 = p2; p2 = p3; p3 = p4; p4 = p5;
        int nts = ts + 6; nts = (nts < T_) ? nts : (T_ - 1);
        p5 = dp[(long)nts * H_];

        mem = mem * a1 + om1 * cur - sp;
        sp  = (mem > 1.0f) ? 1.0f : 0.0f;
        unsigned long long msk = __ballot(mem > 1.0f);
        if (lane == 0) op[(long)ts * 16] = msk;
    }
}

// ---------------------------------------------------------------------------
// Kernel C2: d2 dots. 2000 blocks x 32 rows, 2-row ILP.
// ---------------------------------------------------------------------------
__global__ __launch_bounds__(256) void readout_dots(
    const unsigned long long* __restrict__ spk,  // [M_, 16]
    const float* __restrict__ W2,                // [O_, H_]
    float* __restrict__ d2t)                     // idx o*M_ + ts*256 + b
{
    const int t = threadIdx.x, wave = t >> 6, lane = t & 63;

    float w2r[5][16];
#pragma unroll
    for (int oo = 0; oo < 5; ++oo)
#pragma unroll
        for (int q = 0; q < 4; ++q)
            *(float4*)&w2r[oo][4 * q] =
                *(const float4*)&W2[(wave * 5 + oo) * H_ + lane * 16 + 4 * q];

    const int rbase = blockIdx.x * 32;           // M_ = 2000*32
    int b0 = rbase / T_;
    int ts0 = rbase - b0 * T_;

    for (int i = 0; i < 32; i += 2) {
        int r0 = rbase + i, r1 = r0 + 1;
        unsigned long long bw0 = spk[(long)r0 * 16 + (lane >> 2)];
        unsigned long long bw1 = spk[(long)r1 * 16 + (lane >> 2)];
        unsigned int bits0 = (unsigned int)(bw0 >> ((lane & 3) * 16)) & 0xFFFFu;
        unsigned int bits1 = (unsigned int)(bw1 >> ((lane & 3) * 16)) & 0xFFFFu;
        float pa0[5] = {0, 0, 0, 0, 0}, pa1[5] = {0, 0, 0, 0, 0};
#pragma unroll
        for (int j = 0; j < 16; ++j) {
            float f0 = (bits0 >> j) & 1u ? 1.0f : 0.0f;
            float f1 = (bits1 >> j) & 1u ? 1.0f : 0.0f;
#pragma unroll
            for (int oo = 0; oo < 5; ++oo) {
                pa0[oo] = fmaf(f0, w2r[oo][j], pa0[oo]);
                pa1[oo] = fmaf(f1, w2r[oo][j], pa1[oo]);
            }
        }
#pragma unroll
        for (int m = 1; m < 64; m <<= 1)
#pragma unroll
            for (int oo = 0; oo < 5; ++oo) {
                pa0[oo] += __shfl_xor(pa0[oo], m, 64);
                pa1[oo] += __shfl_xor(pa1[oo], m, 64);
            }
        if (lane == 0) {
            int bA = b0, tsA = ts0 + i;
            if (tsA >= T_) { tsA -= T_; bA += 1; }   // rbase%2==0, i even: safe
            int bB = bA, tsB = tsA + 1;
            if (tsB >= T_) { tsB = 0; bB += 1; }
#pragma unroll
            for (int oo = 0; oo < 5; ++oo) {
                d2t[(long)(wave * 5 + oo) * M_ + tsA * 256 + bA] = pa0[oo];
                d2t[(long)(wave * 5 + oo) * M_ + tsB * 256 + bB] = pa1[oo];
            }
        }
    }
}

// ---------------------------------------------------------------------------
// Kernel C3: mem2 linear recurrence. grid (20 o x 4 b-chunks), 64 threads.
// ---------------------------------------------------------------------------
__global__ __launch_bounds__(64) void mem2_scan(
    const float* __restrict__ d2t,   // (o, ts, b)
    const float* __restrict__ tau2, const float* __restrict__ b2,
    float* __restrict__ m2t)         // (o, ts, b)
{
    const int o = blockIdx.x;                    // 0..19
    const int b = blockIdx.y * 64 + threadIdx.x; // 0..255
    float tv  = tau2[o];
    float a2  = 1.0f / (1.0f + __expf(-tv));
    float om2 = 1.0f - a2;
    float bv  = b2[o];

    const float* dp = d2t + (long)o * M_ + b;
    float*       mp = m2t + (long)o * M_ + b;
    float mem = 0.f;

    float p0 = dp[0], p1 = dp[256], p2 = dp[512], p3 = dp[768];
    for (int ts = 0; ts < T_; ++ts) {
        float cur = p0; p0 = p1; p1 = p2; p2 = p3;
        int nts = ts + 4; nts = (nts < T_) ? nts : (T_ - 1);
        p3 = dp[(long)nts * 256];
        mem = mem * a2 + om2 * (cur + bv);
        mp[(long)ts * 256] = mem;
    }
}

// ---------------------------------------------------------------------------
// Kernel C4: per-(b,ts) softmax in-register + per-b sum over ts via LDS.
// ---------------------------------------------------------------------------
__global__ __launch_bounds__(256) void softmax_acc(
    const float* __restrict__ m2t,   // (o, ts, b)
    float* __restrict__ out)         // [B_, O_]
{
    __shared__ float sp[T_][O_];     // 19.5 KB
    const int b  = blockIdx.x;
    const int ts = threadIdx.x;

    if (ts < T_) {
        if (ts > 10) {
            float m[O_];
#pragma unroll
            for (int o = 0; o < O_; ++o)
                m[o] = m2t[(long)o * M_ + ts * 256 + b];
            float mx = m[0];
#pragma unroll
            for (int o = 1; o < O_; ++o) mx = fmaxf(mx, m[o]);
            float s = 0.f;
#pragma unroll
            for (int o = 0; o < O_; ++o) { m[o] = __expf(m[o] - mx); s += m[o]; }
            float inv = 1.0f / s;
#pragma unroll
            for (int o = 0; o < O_; ++o) sp[ts][o] = m[o] * inv;
        } else {
#pragma unroll
            for (int o = 0; o < O_; ++o) sp[ts][o] = 0.f;
        }
    }
    __syncthreads();
    if (ts < O_) {
        float s = 0.f;
        for (int k = 11; k < T_; ++k) s += sp[k][ts];
        out[b * O_ + ts] = s;
    }
}

// ---------------------------------------------------------------------------
extern "C" void kernel_launch(void* const* d_in, const int* in_sizes, int n_in,
                              void* d_out, int out_size, void* d_ws, size_t ws_size,
                              hipStream_t stream)
{
    const float* X    = (const float*)d_in[0];
    const float* W1   = (const float*)d_in[1];
    const float* b1   = (const float*)d_in[2];
    const float* tau1 = (const float*)d_in[3];
    const float* W2   = (const float*)d_in[4];
    const float* b2   = (const float*)d_in[5];
    const float* tau2 = (const float*)d_in[6];
    float* out = (float*)d_out;

    // Workspace layout kept from previous rounds (Xhi/Xlo regions are now
    // only used as spk/d2t scratch aliases; no X split is materialized).
    unsigned short* Xhi  = (unsigned short*)d_ws;
    unsigned short* Xlo  = Xhi + (long)M_ * KP;
    unsigned short* W1hi = Xlo + (long)M_ * KP;
    unsigned short* W1lo = W1hi + (long)H_ * KP;
    float* d1 = (float*)(W1lo + (long)H_ * KP);  // [M_, H] fp32

    unsigned long long* spk = (unsigned long long*)Xhi;      // scratch
    float* d2t = (float*)Xlo;                                // scratch
    float* m2t = d2t + (long)O_ * M_;

    // 1. split conversion: W1 only (X split fused into gemm A-staging)
    {
        int chunks = H_ * (KP / 8);
        split_convert<<<(chunks + 255) / 256, 256, 0, stream>>>(W1, W1hi, W1lo, H_, D_, KP);
    }

    // 2. d1 = X @ W1^T + b1  (256^2 tile, 1000 blocks = 250 m x 4 n)
    gemm256<<<dim3(1000), dim3(512), 0, stream>>>(X, W1hi, W1lo, b1, d1);

    // 3. layer-1 spike scan
    {
        dim3 grid(H_ / 256, B_);                 // (4, 256)
        lif_spikes<<<grid, 256, 0, stream>>>(d1, tau1, spk);
    }

    // 4. readout dots
    readout_dots<<<M_ / 32, 256, 0, stream>>>(spk, W2, d2t);

    // 5. mem2 linear scan
    {
        dim3 grid(O_, 4);
        mem2_scan<<<grid, 64, 0, stream>>>(d2t, tau2, b2, m2t);
    }

    // 6. softmax + accumulate
    softmax_acc<<<B_, 256, 0, stream>>>(m2t, out);
}